// Round 2
// baseline (266.702 us; speedup 1.0000x reference)
//
#include <hip/hip_runtime.h>
#include <stdint.h>

#define BATCHES 64
#define IMG_W 512
#define IMG_ELEMS (512 * 512)
#define PS 8
#define NP 32
#define NPOS_W 505
#define NPOS (505 * 505)
#define TPB 512
#define BPB 16            /* blocks per batch */
#define F4T 8             /* float4 loads per thread: 65536/(16*512) */
#define NSORT 512

typedef unsigned long long u64;

// Monotone float->uint transform: uint order == float order.
__device__ __forceinline__ unsigned int f2sortable(float f) {
    unsigned int u = __float_as_uint(f);
    return (u & 0x80000000u) ? ~u : (u | 0x80000000u);
}

// Fused: (a) full-image float4 scan compacting center values > 3.0 into
// per-batch candidate lists, (b) last block per batch bitonic-sorts the
// candidates (key = sortable_val<<32 | ~idx reproduces jax top_k order:
// value desc, lower index on ties) and gathers the 32 8x8 patches.
__global__ __launch_bounds__(TPB) void patchify_fused(
    const float* __restrict__ x,
    int* __restrict__ counts,
    int* __restrict__ done,
    u64* __restrict__ cands,
    float* __restrict__ out,
    int cap)
{
    __shared__ u64 skeys[NSORT];
    __shared__ u64 topk[NP];
    __shared__ int amLast;

    const int b = blockIdx.x >> 4;
    const int chunk = blockIdx.x & (BPB - 1);
    const int tid = threadIdx.x;
    const float* img = x + (size_t)b * IMG_ELEMS;
    const float4* img4 = (const float4*)img;

    // ---- scan: 8 independent float4 loads, fully unrolled ----
    float4 v[F4T];
    const int base = chunk * (TPB * F4T) + tid;
#pragma unroll
    for (int k = 0; k < F4T; ++k) v[k] = img4[base + k * TPB];

#pragma unroll
    for (int k = 0; k < F4T; ++k) {
        const int m = base + k * TPB;   // float4 index within image
        const int f = m << 2;           // flat float index
        const int i = f >> 9;           // row (same for all 4 elems)
        const int j = f & 511;          // col of element 0
        if (i >= 4 && i <= 508) {
            const float vv[4] = {v[k].x, v[k].y, v[k].z, v[k].w};
#pragma unroll
            for (int e = 0; e < 4; ++e) {
                const int c = j + e;
                if (vv[e] > 3.0f && c >= 4 && c <= 508) {
                    int slot = atomicAdd(&counts[b], 1);
                    if (slot < cap) {
                        unsigned int q = (unsigned int)((i - 4) * NPOS_W + (c - 4));
                        cands[(size_t)b * cap + slot] =
                            ((u64)f2sortable(vv[e]) << 32) | (u64)(~q);
                    }
                }
            }
        }
    }

    // ---- last-block handoff (release: fence all stores, then count) ----
    __threadfence();
    __syncthreads();
    if (tid == 0) {
        int t = atomicAdd(&done[b], 1);
        amLast = (t == BPB - 1);
    }
    __syncthreads();
    if (!amLast) return;
    __threadfence();  // acquire side

    const int count = atomicAdd(&counts[b], 0);
    const bool fast = (count >= NP) && (count <= cap) && (cap >= NP);

    if (fast) {
        skeys[tid] = (tid < count) ? cands[(size_t)b * cap + tid] : 0ull;
        __syncthreads();
        // bitonic sort, descending; padding zeros sink (real keys have MSB set)
        for (int k = 2; k <= NSORT; k <<= 1) {
            for (int j = k >> 1; j > 0; j >>= 1) {
                int ixj = tid ^ j;
                if (ixj > tid) {
                    u64 a = skeys[tid];
                    u64 c2 = skeys[ixj];
                    bool desc = ((tid & k) == 0);
                    if ((a < c2) == desc) { skeys[tid] = c2; skeys[ixj] = a; }
                }
                __syncthreads();
            }
        }
        if (tid < NP) topk[tid] = skeys[tid];
        __syncthreads();
    } else {
        // exact fallback (statistically never taken): 32 rounds of block max
        u64 prev = ~0ull;
        for (int sel = 0; sel < NP; ++sel) {
            u64 best = 0ull;
            for (int q = tid; q < NPOS; q += TPB) {
                int r = q / NPOS_W;
                int c0 = q - r * NPOS_W;
                float val = img[(r + 4) * IMG_W + (c0 + 4)];
                u64 key = ((u64)f2sortable(val) << 32) | (u64)(~(unsigned int)q);
                if (key < prev && key > best) best = key;
            }
            skeys[tid] = best;
            __syncthreads();
            for (int s = TPB / 2; s > 0; s >>= 1) {
                if (tid < s) {
                    if (skeys[tid + s] > skeys[tid]) skeys[tid] = skeys[tid + s];
                }
                __syncthreads();
            }
            prev = skeys[0];
            if (tid == 0) topk[sel] = prev;
            __syncthreads();
        }
    }

    // ---- gather: 32 patches x 64 elems, coalesced writes ----
    for (int e = tid; e < NP * PS * PS; e += TPB) {
        int p = e >> 6;
        int rem = e & 63;
        int pi = rem >> 3;
        int pj = rem & 7;
        unsigned int q = ~(unsigned int)(topk[p] & 0xFFFFFFFFull);
        unsigned int r = q / NPOS_W;
        unsigned int c = q - r * NPOS_W;
        out[((size_t)b * NP + p) * (PS * PS) + rem] = img[(r + pi) * IMG_W + (c + pj)];
    }
}

extern "C" void kernel_launch(void* const* d_in, const int* in_sizes, int n_in,
                              void* d_out, int out_size, void* d_ws, size_t ws_size,
                              hipStream_t stream) {
    const float* x = (const float*)d_in[0];
    float* out = (float*)d_out;

    int* counts = (int*)d_ws;                       // 64 ints
    int* done = (int*)((char*)d_ws + 256);          // 64 ints
    u64* cands = (u64*)((char*)d_ws + 1024);
    int cap = 0;
    if (ws_size > 1024) {
        size_t c = (ws_size - 1024) / ((size_t)BATCHES * sizeof(u64));
        cap = (int)(c > (size_t)NSORT ? (size_t)NSORT : c);
    }

    hipMemsetAsync(d_ws, 0, 512, stream);  // zero counts + done
    patchify_fused<<<dim3(BATCHES * BPB), dim3(TPB), 0, stream>>>(
        x, counts, done, cands, out, cap);
}

// Round 3
// 161.237 us; speedup vs baseline: 1.6541x; 1.6541x over previous
//
#include <hip/hip_runtime.h>
#include <stdint.h>

#define BATCHES 64
#define IMG_W 512
#define IMG_ELEMS (512 * 512)
#define PS 8
#define NP 32
#define NPOS_W 505
#define NPOS (505 * 505)
#define CHUNKS 32          /* blocks per batch in collect */
#define CTPB 256           /* collect threads per block */
#define F4T 8              /* float4 loads per thread: 65536/(32*256) */
#define STPB 512           /* select threads per block */
#define NSORT 512          /* candidate capacity for fast path */

typedef unsigned long long u64;

// Monotone float->uint transform: uint order == float order.
__device__ __forceinline__ unsigned int f2sortable(float f) {
    unsigned int u = __float_as_uint(f);
    return (u & 0x80000000u) ? ~u : (u | 0x80000000u);
}

// Pass 1: vectorized scan of the whole image; compact center values > 3.0
// into per-batch candidate lists with wave-aggregated atomics.
// key = (sortable_val<<32) | ~idx  -> descending key order == jax top_k
// order (value desc, lower index first on ties).
__global__ __launch_bounds__(CTPB) void collect_kernel(
    const float* __restrict__ x,
    int* __restrict__ counts,
    u64* __restrict__ cands,
    int cap)
{
    const int b = blockIdx.x >> 5;
    const int chunk = blockIdx.x & (CHUNKS - 1);
    const float* img = x + (size_t)b * IMG_ELEMS;
    const float4* img4 = (const float4*)img;
    const int lane = threadIdx.x & 63;

    const int base = chunk * (CTPB * F4T) + threadIdx.x;
    float4 v[F4T];
#pragma unroll
    for (int k = 0; k < F4T; ++k) v[k] = img4[base + k * CTPB];

#pragma unroll
    for (int k = 0; k < F4T; ++k) {
        const int f = (base + k * CTPB) << 2;  // flat float index
        const int i = f >> 9;                  // row
        const int j = f & 511;                 // col of element 0
        const float vv[4] = {v[k].x, v[k].y, v[k].z, v[k].w};
#pragma unroll
        for (int e = 0; e < 4; ++e) {
            const int c = j + e;
            const bool pred = (vv[e] > 3.0f) & (i >= 4) & (i <= 508) &
                              (c >= 4) & (c <= 508);
            u64 mask = __ballot(pred);
            if (pred) {
                int lower = __popcll(mask & ((1ull << lane) - 1ull));
                int first = __ffsll((long long)mask) - 1;
                int base_slot = 0;
                if (lane == first)
                    base_slot = atomicAdd(&counts[b], __popcll(mask));
                base_slot = __shfl(base_slot, first);
                int slot = base_slot + lower;
                if (slot < cap) {
                    unsigned int q = (unsigned int)((i - 4) * NPOS_W + (c - 4));
                    cands[(size_t)b * cap + slot] =
                        ((u64)f2sortable(vv[e]) << 32) | (u64)(~q);
                }
            }
        }
    }
}

// Pass 2: per batch, exact top-32 by O(c^2) rank selection over the ~344
// candidates (LDS broadcast reads), then gather the 32 8x8 patches.
// Exact slow fallback if candidate count is out of range (never taken
// statistically).
__global__ __launch_bounds__(STPB) void select_gather_kernel(
    const float* __restrict__ x,
    const int* __restrict__ counts,
    const u64* __restrict__ cands,
    float* __restrict__ out,
    int cap)
{
    __shared__ u64 skeys[NSORT];
    __shared__ u64 topk[NP];
    const int b = blockIdx.x;
    const int tid = threadIdx.x;
    const float* img = x + (size_t)b * IMG_ELEMS;
    const int count = counts[b];
    const bool fast = (count >= NP) && (count <= cap) && (count <= NSORT) &&
                      (cap >= NP);

    if (fast) {
        if (tid < count) skeys[tid] = cands[(size_t)b * cap + tid];
        __syncthreads();
        if (tid < count) {
            const u64 mykey = skeys[tid];
            int rank = 0;
            for (int i = 0; i < count; ++i) rank += (skeys[i] > mykey);
            if (rank < NP) topk[rank] = mykey;  // keys unique -> ranks unique
        }
        __syncthreads();
    } else {
        // exact fallback: 32 rounds of block-wide max below previous key
        u64 prev = ~0ull;
        for (int sel = 0; sel < NP; ++sel) {
            u64 best = 0ull;
            for (int q = tid; q < NPOS; q += STPB) {
                int r = q / NPOS_W;
                int c0 = q - r * NPOS_W;
                float val = img[(r + 4) * IMG_W + (c0 + 4)];
                u64 key = ((u64)f2sortable(val) << 32) | (u64)(~(unsigned int)q);
                if (key < prev && key > best) best = key;
            }
            skeys[tid] = best;
            __syncthreads();
            for (int s = STPB / 2; s > 0; s >>= 1) {
                if (tid < s) {
                    if (skeys[tid + s] > skeys[tid]) skeys[tid] = skeys[tid + s];
                }
                __syncthreads();
            }
            prev = skeys[0];
            if (tid == 0) topk[sel] = prev;
            __syncthreads();
        }
    }

    // gather: 32 patches x 64 elems, coalesced writes
    for (int e = tid; e < NP * PS * PS; e += STPB) {
        int p = e >> 6;
        int rem = e & 63;
        int pi = rem >> 3;
        int pj = rem & 7;
        unsigned int q = ~(unsigned int)(topk[p] & 0xFFFFFFFFull);
        unsigned int r = q / NPOS_W;
        unsigned int c = q - r * NPOS_W;
        out[((size_t)b * NP + p) * (PS * PS) + rem] = img[(r + pi) * IMG_W + (c + pj)];
    }
}

extern "C" void kernel_launch(void* const* d_in, const int* in_sizes, int n_in,
                              void* d_out, int out_size, void* d_ws, size_t ws_size,
                              hipStream_t stream) {
    const float* x = (const float*)d_in[0];
    float* out = (float*)d_out;

    int* counts = (int*)d_ws;                   // 64 ints
    u64* cands = (u64*)((char*)d_ws + 1024);
    int cap = 0;
    if (ws_size > 1024) {
        size_t c = (ws_size - 1024) / ((size_t)BATCHES * sizeof(u64));
        cap = (int)(c > (size_t)NSORT ? (size_t)NSORT : c);
    }

    hipMemsetAsync(counts, 0, BATCHES * sizeof(int), stream);
    collect_kernel<<<dim3(BATCHES * CHUNKS), dim3(CTPB), 0, stream>>>(
        x, counts, cands, cap);
    select_gather_kernel<<<dim3(BATCHES), dim3(STPB), 0, stream>>>(
        x, counts, cands, out, cap);
}

// Round 4
// 28.910 us; speedup vs baseline: 9.2253x; 5.5772x over previous
//
#include <hip/hip_runtime.h>
#include <stdint.h>

#define BATCHES 64
#define IMG_W 512
#define IMG_ELEMS (512 * 512)
#define PS 8
#define NP 32
#define NPOS_W 505
#define NPOS (505 * 505)
#define CHUNKS 32          /* blocks per batch in collect */
#define CTPB 256           /* collect threads per block */
#define F4T 8              /* float4 loads per thread: 65536/(32*256) */
#define STPB 512           /* select threads per block */
#define NSORT 512          /* max total candidates for fast path */
#define SEGMAX 64          /* per-chunk candidate segment capacity */

typedef unsigned long long u64;

// Monotone float->uint transform: uint order == float order.
__device__ __forceinline__ unsigned int f2sortable(float f) {
    unsigned int u = __float_as_uint(f);
    return (u & 0x80000000u) ? ~u : (u | 0x80000000u);
}

// Pass 1: vectorized scan; each (batch,chunk) block compacts center values
// > 3.0 into its OWN disjoint segment using a block-local LDS counter.
// No global atomics anywhere. key = (sortable_val<<32) | ~idx  ->
// descending key order == jax top_k order (value desc, low index on ties).
__global__ __launch_bounds__(CTPB) void collect_kernel(
    const float* __restrict__ x,
    int* __restrict__ counts,          /* [BATCHES*CHUNKS] */
    u64* __restrict__ cands,           /* [BATCHES*CHUNKS*seg] */
    int seg)
{
    __shared__ int lcount;
    const int b = blockIdx.x >> 5;
    const int chunk = blockIdx.x & (CHUNKS - 1);
    if (threadIdx.x == 0) lcount = 0;
    __syncthreads();

    const float4* img4 = (const float4*)(x + (size_t)b * IMG_ELEMS);
    const int base = chunk * (CTPB * F4T) + threadIdx.x;
    float4 v[F4T];
#pragma unroll
    for (int k = 0; k < F4T; ++k) v[k] = img4[base + k * CTPB];

    u64* myseg = cands + ((size_t)b * CHUNKS + chunk) * (size_t)seg;

#pragma unroll
    for (int k = 0; k < F4T; ++k) {
        const int f = (base + k * CTPB) << 2;  // flat float index
        const int i = f >> 9;                  // row
        const int j = f & 511;                 // col of element 0
        const float vv[4] = {v[k].x, v[k].y, v[k].z, v[k].w};
#pragma unroll
        for (int e = 0; e < 4; ++e) {
            const int c = j + e;
            if (vv[e] > 3.0f && i >= 4 && i <= 508 && c >= 4 && c <= 508) {
                int slot = atomicAdd(&lcount, 1);   // LDS atomic, block-local
                if (slot < seg) {
                    unsigned int q = (unsigned int)((i - 4) * NPOS_W + (c - 4));
                    myseg[slot] = ((u64)f2sortable(vv[e]) << 32) | (u64)(~q);
                }
            }
        }
    }
    __syncthreads();
    if (threadIdx.x == 0) counts[b * CHUNKS + chunk] = lcount;  // plain store
}

// Pass 2: per batch, concatenate the 32 segments in LDS, exact top-32 by
// O(c^2) rank selection (~344 candidates), then gather the 32 8x8 patches.
// Exact slow fallback if any segment overflowed or total out of range.
__global__ __launch_bounds__(STPB) void select_gather_kernel(
    const float* __restrict__ x,
    const int* __restrict__ counts,
    const u64* __restrict__ cands,
    float* __restrict__ out,
    int seg)
{
    __shared__ u64 skeys[NSORT];
    __shared__ u64 topk[NP];
    __shared__ int cnt[CHUNKS];
    __shared__ int pfx[CHUNKS + 1];
    __shared__ int okf;
    const int b = blockIdx.x;
    const int tid = threadIdx.x;
    const float* img = x + (size_t)b * IMG_ELEMS;

    if (tid < CHUNKS) cnt[tid] = counts[b * CHUNKS + tid];
    if (tid == 0) okf = 1;
    __syncthreads();
    if (tid == 0) {
        int s = 0;
        for (int c = 0; c < CHUNKS; ++c) {
            pfx[c] = s;
            s += cnt[c];
            if (cnt[c] > seg) okf = 0;
        }
        pfx[CHUNKS] = s;
        if (s < NP || s > NSORT) okf = 0;
    }
    __syncthreads();
    const int total = pfx[CHUNKS];
    const bool fast = (okf != 0) && (seg >= 1);

    if (fast) {
        for (int idx = tid; idx < CHUNKS * seg; idx += STPB) {
            int c = idx / seg;
            int i = idx - c * seg;
            if (i < cnt[c])
                skeys[pfx[c] + i] = cands[((size_t)b * CHUNKS + c) * (size_t)seg + i];
        }
        __syncthreads();
        if (tid < total) {
            const u64 mykey = skeys[tid];
            int rank = 0;
            for (int i = 0; i < total; ++i) rank += (skeys[i] > mykey);
            if (rank < NP) topk[rank] = mykey;  // keys unique -> ranks unique
        }
        __syncthreads();
    } else {
        // exact fallback: 32 rounds of block-wide max below previous key
        u64 prev = ~0ull;
        for (int sel = 0; sel < NP; ++sel) {
            u64 best = 0ull;
            for (int q = tid; q < NPOS; q += STPB) {
                int r = q / NPOS_W;
                int c0 = q - r * NPOS_W;
                float val = img[(r + 4) * IMG_W + (c0 + 4)];
                u64 key = ((u64)f2sortable(val) << 32) | (u64)(~(unsigned int)q);
                if (key < prev && key > best) best = key;
            }
            skeys[tid] = best;
            __syncthreads();
            for (int s = STPB / 2; s > 0; s >>= 1) {
                if (tid < s) {
                    if (skeys[tid + s] > skeys[tid]) skeys[tid] = skeys[tid + s];
                }
                __syncthreads();
            }
            prev = skeys[0];
            if (tid == 0) topk[sel] = prev;
            __syncthreads();
        }
    }

    // gather: 32 patches x 64 elems, coalesced writes
    for (int e = tid; e < NP * PS * PS; e += STPB) {
        int p = e >> 6;
        int rem = e & 63;
        int pi = rem >> 3;
        int pj = rem & 7;
        unsigned int q = ~(unsigned int)(topk[p] & 0xFFFFFFFFull);
        unsigned int r = q / NPOS_W;
        unsigned int c = q - r * NPOS_W;
        out[((size_t)b * NP + p) * (PS * PS) + rem] = img[(r + pi) * IMG_W + (c + pj)];
    }
}

extern "C" void kernel_launch(void* const* d_in, const int* in_sizes, int n_in,
                              void* d_out, int out_size, void* d_ws, size_t ws_size,
                              hipStream_t stream) {
    const float* x = (const float*)d_in[0];
    float* out = (float*)d_out;

    int* counts = (int*)d_ws;  // BATCHES*CHUNKS ints = 8 KB
    u64* cands = (u64*)((char*)d_ws + 8192);
    int seg = 0;
    if (ws_size > 8192) {
        size_t s = (ws_size - 8192) / ((size_t)BATCHES * CHUNKS * sizeof(u64));
        seg = (int)(s > (size_t)SEGMAX ? (size_t)SEGMAX : s);
    }

    collect_kernel<<<dim3(BATCHES * CHUNKS), dim3(CTPB), 0, stream>>>(
        x, counts, cands, seg);
    select_gather_kernel<<<dim3(BATCHES), dim3(STPB), 0, stream>>>(
        x, counts, cands, out, seg);
}